// Round 9
// baseline (219.030 us; speedup 1.0000x reference)
//
#include <hip/hip_runtime.h>

#define N_NODES 50000
#define N_EDGES 800000
#define D 128
#define NBLK ((N_NODES + 255) / 256)   // 196 coarse buckets (dst>>8)
#define EPB 4096                        // edges per stage block
#define CAP 8192                        // staged capacity per coarse bucket (true edges)
#define PCAP 8192                       // padded eidx capacity per bucket (sum ceil(d/16)*16 <= 7936)

typedef __bf16 bf16x8 __attribute__((ext_vector_type(8)));
typedef short s16x8 __attribute__((ext_vector_type(8)));
typedef float f32x4 __attribute__((ext_vector_type(4)));
typedef unsigned short u16;
typedef unsigned int u32;
typedef u32 u32x4 __attribute__((ext_vector_type(4)));

__device__ inline u16 f32_to_bf16(float f) {
    u32 u = __builtin_bit_cast(u32, f);
    u += 0x7fffu + ((u >> 16) & 1u);   // round-to-nearest-even
    return (u16)(u >> 16);
}
__device__ inline float bf16_lo(u32 v) { return __builtin_bit_cast(float, v << 16); }
__device__ inline float bf16_hi(u32 v) { return __builtin_bit_cast(float, v & 0xffff0000u); }

__device__ inline f32x4 mfma16(s16x8 a, s16x8 b, f32x4 c) {
    return __builtin_amdgcn_mfma_f32_16x16x32_bf16(
        __builtin_bit_cast(bf16x8, a), __builtin_bit_cast(bf16x8, b), c, 0, 0, 0);
}

#define CAST_BLOCKS ((N_NODES * 16) / 256)            // 3125
#define STAGE_BLOCKS ((N_EDGES + EPB - 1) / EPB)      // 196

// Merged: cast x->bf16 | pack weights | coarse-stage edges | zero-row init.
__global__ __launch_bounds__(256) void prep_stage(
    const float* __restrict__ x, u16* __restrict__ xb, u16* __restrict__ hb,
    const float* __restrict__ W0l, const float* __restrict__ W0r,
    const float* __restrict__ W1l, const float* __restrict__ W1r,
    u16* __restrict__ Wp,
    const int* __restrict__ src, const int* __restrict__ dst,
    int* __restrict__ ccount, u32* __restrict__ staged) {
    __shared__ int hist[NBLK];
    __shared__ int base[NBLK];
    int t = threadIdx.x, b = blockIdx.x;
    if (b < CAST_BLOCKS) {
        int gid = b * 256 + t;                       // < N_NODES*16
        const float* p = x + (size_t)gid * 8;
        f32x4 a = *(const f32x4*)p;
        f32x4 c = *(const f32x4*)(p + 4);
        u16 o[8];
#pragma unroll
        for (int j = 0; j < 4; j++) { o[j] = f32_to_bf16(a[j]); o[4 + j] = f32_to_bf16(c[j]); }
        *(s16x8*)(xb + (size_t)gid * 8) = *(const s16x8*)o;
    } else if (b < CAST_BLOCKS + 32) {
        int gid = (b - CAST_BLOCKS) * 256 + t;       // < 8192
        int wsel = gid >> 11;
        int rem  = gid & 2047;
        int ct   = rem >> 8;         // 0..7
        int ks   = (rem >> 6) & 3;   // 0..3
        int lane = rem & 63;
        const float* W = (wsel == 0) ? W0l : (wsel == 1) ? W0r : (wsel == 2) ? W1l : W1r;
        int n  = ct * 16 + (lane & 15);
        int k0 = ks * 32 + (lane >> 4) * 8;
        u16 o[8];
#pragma unroll
        for (int j = 0; j < 8; j++) o[j] = f32_to_bf16(W[(k0 + j) * D + n]);
        u16* dp = Wp + wsel * 16384 + (size_t)((ct * 4 + ks) * 64 + lane) * 8;
        *(s16x8*)dp = *(const s16x8*)o;
    } else if (b < CAST_BLOCKS + 33) {
        // zero row at index N_NODES for pad gathers (both xb and hb)
        if (t < 64)       ((u32*)(xb + (size_t)N_NODES * D))[t] = 0;
        else if (t < 128) ((u32*)(hb + (size_t)N_NODES * D))[t - 64] = 0;
    } else {
        int sb = b - CAST_BLOCKS - 33;               // 0..195
        int bb = sb * EPB;
        if (t < NBLK) hist[t] = 0;
        __syncthreads();
        u32 pk[16]; int cb[16];
#pragma unroll
        for (int i = 0; i < 16; i++) {
            int e = bb + i * 256 + t;
            if (e < N_EDGES) {
                int sv = src[e], dv = dst[e];
                pk[i] = (u32)sv | ((u32)(dv & 255) << 16);
                cb[i] = dv >> 8;
                atomicAdd(&hist[cb[i]], 1);
            } else cb[i] = -1;
        }
        __syncthreads();
        if (t < NBLK) {
            int c = hist[t];
            if (c > 0) {
                int old = atomicAdd(&ccount[t], c);
                if (old > CAP - c) old = CAP - c;   // safety clamp (never hit for bench input)
                base[t] = t * CAP + old;
            }
            hist[t] = 0;                 // reuse as intra-block slot counters
        }
        __syncthreads();
#pragma unroll
        for (int i = 0; i < 16; i++) {
            if (cb[i] >= 0) {
                int slot = atomicAdd(&hist[cb[i]], 1);
                staged[base[cb[i]] + slot] = pk[i];
            }
        }
    }
}

// Fine: one block per coarse bucket. Bucket-local padded CSR: node's edges padded
// to a multiple of 16 with dummy src N_NODES (zero row). info = base | rounds<<21.
__global__ __launch_bounds__(256) void fine_kernel(const int* __restrict__ ccount,
                                                   const u32* __restrict__ staged,
                                                   u16* __restrict__ eidx,
                                                   u32* __restrict__ info,
                                                   float* __restrict__ inv) {
    __shared__ u32 sdata[CAP];
    __shared__ int hist[256];
    __shared__ int cursor[256];
    __shared__ int wsum[4];
    int t = threadIdx.x, cb = blockIdx.x;
    int lane = t & 63, wave = t >> 6;

    hist[t] = 0;
    __syncthreads();
    int c = ccount[cb];
    if (c > CAP) c = CAP;
    for (int i = t; i < c; i += 256) {
        u32 v = staged[cb * CAP + i];
        sdata[i] = v;
        atomicAdd(&hist[(v >> 16) & 255], 1);
    }
    __syncthreads();
    int d = hist[t];                 // true degree
    int pd = (d + 15) & ~15;         // padded length
    int s = pd;
#pragma unroll
    for (int off = 1; off < 64; off <<= 1) {
        int u = __shfl_up(s, off, 64);
        if (lane >= off) s += u;
    }
    if (lane == 63) wsum[wave] = s;
    __syncthreads();
    int wadd = 0;
#pragma unroll
    for (int w = 0; w < 4; w++) if (w < wave) wadd += wsum[w];
    int gb = cb * PCAP + (s - pd + wadd);   // padded base (bucket-local region)
    int node = cb * 256 + t;
    if (node < N_NODES) {
        info[node] = (u32)gb | ((u32)(pd >> 4) << 21);
        inv[node] = d > 0 ? 1.0f / (float)d : 0.0f;
    }
    cursor[t] = gb;
    __syncthreads();
    for (int i = t; i < c; i += 256) {
        u32 v = sdata[i];
        int pos = atomicAdd(&cursor[(v >> 16) & 255], 1);
        eidx[pos] = (u16)(v & 0xffffu);
    }
    // pad-fill with dummy src = N_NODES (zero row)
    for (int i = gb + d; i < gb + pd; i++) eidx[i] = (u16)N_NODES;
}

// Fused SAGE layer, 16-row tile (50000 = 16*3125).
// Phase 1: each wave computes means for 4 nodes, software-pipelined: per round,
//   issue all 4 nodes' eidx loads + 16 dwordx4 gathers (4KB/wave in flight),
//   then accumulate. Padded CSR => no tails, no masks.
// Phase 2: out = A@Wr + mean@Wl + mask*b (+ReLU); mean via swizzled LDS.
template <int RELU, int OUTF32>
__global__ __launch_bounds__(256) void fused_layer(
    const u16* __restrict__ A,
    const u16* __restrict__ WpR, const u16* __restrict__ WpL,
    const float* __restrict__ bias, const float* __restrict__ inv,
    const u32* __restrict__ info, const u16* __restrict__ eidx,
    u16* __restrict__ outb, float* __restrict__ outf) {
    __shared__ char mlds[16 * 256];   // 16 rows x 128 bf16, 16B-chunk XOR swizzle
    int wave = threadIdx.x >> 6, lane = threadIdx.x & 63;
    int rowbase = blockIdx.x * 16;
    int quad = lane >> 4, ql = lane & 15;

    int basek[4], rnds[4];
#pragma unroll
    for (int k = 0; k < 4; k++) {
        u32 ifo = info[rowbase + wave * 4 + k];
        basek[k] = (int)(ifo & 0x1FFFFFu);
        rnds[k]  = (int)(ifo >> 21);
    }
    int maxr = rnds[0];
#pragma unroll
    for (int k = 1; k < 4; k++) maxr = rnds[k] > maxr ? rnds[k] : maxr;

    float acc[4][8];
#pragma unroll
    for (int k = 0; k < 4; k++)
#pragma unroll
        for (int j = 0; j < 8; j++) acc[k][j] = 0.f;

#pragma unroll 1
    for (int r = 0; r < maxr; r++) {
        u32x4 g[4][4];
        // issue all loads first (16 eidx + 16 gathers in flight)
#pragma unroll
        for (int k = 0; k < 4; k++) {
            if (r < rnds[k]) {                         // wave-uniform branch
                int i0 = basek[k] + r * 16 + quad;
                int s0 = eidx[i0], s1 = eidx[i0 + 4], s2 = eidx[i0 + 8], s3 = eidx[i0 + 12];
                g[k][0] = *(const u32x4*)(A + (size_t)s0 * D + ql * 8);
                g[k][1] = *(const u32x4*)(A + (size_t)s1 * D + ql * 8);
                g[k][2] = *(const u32x4*)(A + (size_t)s2 * D + ql * 8);
                g[k][3] = *(const u32x4*)(A + (size_t)s3 * D + ql * 8);
            }
        }
        // then accumulate
#pragma unroll
        for (int k = 0; k < 4; k++) {
            if (r < rnds[k]) {
#pragma unroll
                for (int j = 0; j < 4; j++) {
                    u32x4 v = g[k][j];
                    acc[k][0] += bf16_lo(v.x); acc[k][1] += bf16_hi(v.x);
                    acc[k][2] += bf16_lo(v.y); acc[k][3] += bf16_hi(v.y);
                    acc[k][4] += bf16_lo(v.z); acc[k][5] += bf16_hi(v.z);
                    acc[k][6] += bf16_lo(v.w); acc[k][7] += bf16_hi(v.w);
                }
            }
        }
    }

#pragma unroll
    for (int k = 0; k < 4; k++) {
#pragma unroll
        for (int j = 0; j < 8; j++) {
            acc[k][j] += __shfl_xor(acc[k][j], 16);
            acc[k][j] += __shfl_xor(acc[k][j], 32);
        }
        if (quad == 0) {
            int node = rowbase + wave * 4 + k;
            float iv = inv[node];
            u32x4 o;
            o.x = (u32)f32_to_bf16(acc[k][0] * iv) | ((u32)f32_to_bf16(acc[k][1] * iv) << 16);
            o.y = (u32)f32_to_bf16(acc[k][2] * iv) | ((u32)f32_to_bf16(acc[k][3] * iv) << 16);
            o.z = (u32)f32_to_bf16(acc[k][4] * iv) | ((u32)f32_to_bf16(acc[k][5] * iv) << 16);
            o.w = (u32)f32_to_bf16(acc[k][6] * iv) | ((u32)f32_to_bf16(acc[k][7] * iv) << 16);
            int lr = wave * 4 + k;
            *(u32x4*)(mlds + lr * 256 + ((ql ^ lr) & 15) * 16) = o;
        }
    }

    // B fragments loaded after the gather to keep gather-phase register pressure low.
    s16x8 bR[2][4], bL[2][4];
#pragma unroll
    for (int ct = 0; ct < 2; ct++) {
        int ctg = wave * 2 + ct;
#pragma unroll
        for (int ks = 0; ks < 4; ks++) {
            size_t off = (size_t)((ctg * 4 + ks) * 64 + lane) * 8;
            bR[ct][ks] = *(const s16x8*)(WpR + off);
            bL[ct][ks] = *(const s16x8*)(WpL + off);
        }
    }
    __syncthreads();

    // Phase 2: 16x128 GEMM; wave w owns cols [w*32, w*32+32).
    f32x4 acc2[2];
    acc2[0] = (f32x4){0.f, 0.f, 0.f, 0.f};
    acc2[1] = (f32x4){0.f, 0.f, 0.f, 0.f};
#pragma unroll
    for (int ks = 0; ks < 4; ks++) {
        s16x8 a1 = *(const s16x8*)(A + (size_t)(rowbase + ql) * D + ks * 32 + quad * 8);
        s16x8 a2 = *(const s16x8*)(mlds + ql * 256 + (((ks * 4 + quad) ^ ql) & 15) * 16);
#pragma unroll
        for (int ct = 0; ct < 2; ct++) {
            acc2[ct] = mfma16(a1, bR[ct][ks], acc2[ct]);
            acc2[ct] = mfma16(a2, bL[ct][ks], acc2[ct]);
        }
    }

    float bv[2];
#pragma unroll
    for (int ct = 0; ct < 2; ct++) bv[ct] = bias[wave * 32 + ct * 16 + ql];

#pragma unroll
    for (int i = 0; i < 4; i++) {
        int row = rowbase + quad * 4 + i;
        float mask = inv[row] > 0.f ? 1.f : 0.f;
#pragma unroll
        for (int ct = 0; ct < 2; ct++) {
            int col = wave * 32 + ct * 16 + ql;
            float v = acc2[ct][i] + mask * bv[ct];
            if (RELU) v = v > 0.f ? v : 0.f;
            if (OUTF32) outf[(size_t)row * D + col] = v;
            else        outb[(size_t)row * D + col] = f32_to_bf16(v);
        }
    }
}

extern "C" void kernel_launch(void* const* d_in, const int* in_sizes, int n_in,
                              void* d_out, int out_size, void* d_ws, size_t ws_size,
                              hipStream_t stream) {
    const float* x    = (const float*)d_in[0];
    const int*   edge = (const int*)d_in[1];
    const int*   src  = edge;
    const int*   dstn = edge + N_EDGES;
    const float* W0l  = (const float*)d_in[2];
    const float* b0l  = (const float*)d_in[3];
    const float* W0r  = (const float*)d_in[4];
    const float* W1l  = (const float*)d_in[5];
    const float* b1l  = (const float*)d_in[6];
    const float* W1r  = (const float*)d_in[7];
    float* out = (float*)d_out;

    char* p = (char*)d_ws;
    auto alloc = [&](size_t nb) { char* r = p; p += (nb + 255) & ~(size_t)255; return r; };
    int*   ccount = (int*)alloc((size_t)NBLK * 4);
    u32*   info   = (u32*)alloc((size_t)N_NODES * 4);
    float* inv    = (float*)alloc((size_t)N_NODES * 4);
    u32*   staged = (u32*)alloc((size_t)NBLK * CAP * 4);
    u16*   eidx   = (u16*)alloc((size_t)NBLK * PCAP * 2);
    u16*   xb     = (u16*)alloc((size_t)(N_NODES + 1) * D * 2);   // +1 zero row
    u16*   hb     = (u16*)alloc((size_t)(N_NODES + 1) * D * 2);   // +1 zero row
    u16*   Wp     = (u16*)alloc((size_t)4 * 16384 * 2);

    hipMemsetAsync(ccount, 0, (size_t)NBLK * 4, stream);

    prep_stage<<<CAST_BLOCKS + 33 + STAGE_BLOCKS, 256, 0, stream>>>(
        x, xb, hb, W0l, W0r, W1l, W1r, Wp, src, dstn, ccount, staged);
    fine_kernel<<<NBLK, 256, 0, stream>>>(ccount, staged, eidx, info, inv);

    int fblocks = N_NODES / 16;          // 3125 exactly
    const u16* WpL0 = Wp;                 // W0l
    const u16* WpR0 = Wp + 16384;         // W0r
    const u16* WpL1 = Wp + 2 * 16384;     // W1l
    const u16* WpR1 = Wp + 3 * 16384;     // W1r
    // Layer 0: h = relu( x@W0r + mean_x@W0l + mask*b0l )
    fused_layer<1, 0><<<fblocks, 256, 0, stream>>>(xb, WpR0, WpL0, b0l, inv, info, eidx, hb, nullptr);
    // Layer 1: out = h@W1r + mean_h@W1l + mask*b1l
    fused_layer<0, 1><<<fblocks, 256, 0, stream>>>(hb, WpR1, WpL1, b1l, inv, info, eidx, nullptr, out);
}

// Round 10
// 202.800 us; speedup vs baseline: 1.0800x; 1.0800x over previous
//
#include <hip/hip_runtime.h>

#define N_NODES 50000
#define N_EDGES 800000
#define D 128
#define NBLK ((N_NODES + 255) / 256)   // 196 coarse buckets (dst>>8)
#define EPB 4096                        // edges per stage block
#define CAP 8192                        // staged capacity per coarse bucket (true edges)
#define PCAP 8192                       // padded eidx capacity per bucket

typedef __bf16 bf16x8 __attribute__((ext_vector_type(8)));
typedef short s16x8 __attribute__((ext_vector_type(8)));
typedef float f32x4 __attribute__((ext_vector_type(4)));
typedef float f32x2 __attribute__((ext_vector_type(2)));
typedef unsigned short u16;
typedef unsigned int u32;
typedef unsigned char u8;
typedef u32 u32x2 __attribute__((ext_vector_type(2)));
typedef u32 u32x4 __attribute__((ext_vector_type(4)));

__device__ inline u16 f32_to_bf16(float f) {
    u32 u = __builtin_bit_cast(u32, f);
    u += 0x7fffu + ((u >> 16) & 1u);   // round-to-nearest-even
    return (u16)(u >> 16);
}
__device__ inline float bf16_lo(u32 v) { return __builtin_bit_cast(float, v << 16); }
__device__ inline float bf16_hi(u32 v) { return __builtin_bit_cast(float, v & 0xffff0000u); }

__device__ inline f32x4 mfma16(s16x8 a, s16x8 b, f32x4 c) {
    return __builtin_amdgcn_mfma_f32_16x16x32_bf16(
        __builtin_bit_cast(bf16x8, a), __builtin_bit_cast(bf16x8, b), c, 0, 0, 0);
}

#define CAST_BLOCKS ((N_NODES * 16) / 256)            // 3125
#define STAGE_BLOCKS ((N_EDGES + EPB - 1) / EPB)      // 196

// Merged: cast x->bf16+fp8 | pack weights | zero rows | coarse-stage edges.
__global__ __launch_bounds__(256) void prep_stage(
    const float* __restrict__ x, u16* __restrict__ xb, u16* __restrict__ hb,
    u8* __restrict__ xf8, u8* __restrict__ hf8,
    const float* __restrict__ W0l, const float* __restrict__ W0r,
    const float* __restrict__ W1l, const float* __restrict__ W1r,
    u16* __restrict__ Wp,
    const int* __restrict__ src, const int* __restrict__ dst,
    int* __restrict__ ccount, u32* __restrict__ staged) {
    __shared__ int hist[NBLK];
    __shared__ int base[NBLK];
    int t = threadIdx.x, b = blockIdx.x;
    if (b < CAST_BLOCKS) {
        int gid = b * 256 + t;                       // < N_NODES*16
        const float* p = x + (size_t)gid * 8;
        f32x4 a = *(const f32x4*)p;
        f32x4 c = *(const f32x4*)(p + 4);
        u16 o[8];
#pragma unroll
        for (int j = 0; j < 4; j++) { o[j] = f32_to_bf16(a[j]); o[4 + j] = f32_to_bf16(c[j]); }
        *(s16x8*)(xb + (size_t)gid * 8) = *(const s16x8*)o;
        int p0 = __builtin_amdgcn_cvt_pk_fp8_f32(a.x, a.y, 0, false);
        int p1 = __builtin_amdgcn_cvt_pk_fp8_f32(a.z, a.w, 0, false);
        int p2 = __builtin_amdgcn_cvt_pk_fp8_f32(c.x, c.y, 0, false);
        int p3 = __builtin_amdgcn_cvt_pk_fp8_f32(c.z, c.w, 0, false);
        u32x2 w;
        w.x = (u32)(p0 & 0xffff) | ((u32)(p1 & 0xffff) << 16);
        w.y = (u32)(p2 & 0xffff) | ((u32)(p3 & 0xffff) << 16);
        *(u32x2*)(xf8 + (size_t)gid * 8) = w;
    } else if (b < CAST_BLOCKS + 32) {
        int gid = (b - CAST_BLOCKS) * 256 + t;       // < 8192
        int wsel = gid >> 11;
        int rem  = gid & 2047;
        int ct   = rem >> 8;         // 0..7
        int ks   = (rem >> 6) & 3;   // 0..3
        int lane = rem & 63;
        const float* W = (wsel == 0) ? W0l : (wsel == 1) ? W0r : (wsel == 2) ? W1l : W1r;
        int n  = ct * 16 + (lane & 15);
        int k0 = ks * 32 + (lane >> 4) * 8;
        u16 o[8];
#pragma unroll
        for (int j = 0; j < 8; j++) o[j] = f32_to_bf16(W[(k0 + j) * D + n]);
        u16* dp = Wp + wsel * 16384 + (size_t)((ct * 4 + ks) * 64 + lane) * 8;
        *(s16x8*)dp = *(const s16x8*)o;
    } else if (b < CAST_BLOCKS + 33) {
        // zero rows at index N_NODES for pad gathers
        if (t < 64)        ((u32*)(xb + (size_t)N_NODES * D))[t] = 0;
        else if (t < 128)  ((u32*)(hb + (size_t)N_NODES * D))[t - 64] = 0;
        else if (t < 160)  ((u32*)(xf8 + (size_t)N_NODES * D))[t - 128] = 0;
        else if (t < 192)  ((u32*)(hf8 + (size_t)N_NODES * D))[t - 160] = 0;
    } else {
        int sb = b - CAST_BLOCKS - 33;               // 0..195
        int bb = sb * EPB;
        if (t < NBLK) hist[t] = 0;
        __syncthreads();
        u32 pk[16]; int cb[16];
#pragma unroll
        for (int i = 0; i < 16; i++) {
            int e = bb + i * 256 + t;
            if (e < N_EDGES) {
                int sv = src[e], dv = dst[e];
                pk[i] = (u32)sv | ((u32)(dv & 255) << 16);
                cb[i] = dv >> 8;
                atomicAdd(&hist[cb[i]], 1);
            } else cb[i] = -1;
        }
        __syncthreads();
        if (t < NBLK) {
            int c = hist[t];
            if (c > 0) {
                int old = atomicAdd(&ccount[t], c);
                if (old > CAP - c) old = CAP - c;   // safety clamp (never hit for bench input)
                base[t] = t * CAP + old;
            }
            hist[t] = 0;                 // reuse as intra-block slot counters
        }
        __syncthreads();
#pragma unroll
        for (int i = 0; i < 16; i++) {
            if (cb[i] >= 0) {
                int slot = atomicAdd(&hist[cb[i]], 1);
                staged[base[cb[i]] + slot] = pk[i];
            }
        }
    }
}

// Fine: one block per coarse bucket. Bucket-local padded CSR: node's edges padded
// to a multiple of 16 with dummy src N_NODES (zero row). info = base | rounds<<21.
__global__ __launch_bounds__(256) void fine_kernel(const int* __restrict__ ccount,
                                                   const u32* __restrict__ staged,
                                                   u16* __restrict__ eidx,
                                                   u32* __restrict__ info,
                                                   float* __restrict__ inv) {
    __shared__ u32 sdata[CAP];
    __shared__ int hist[256];
    __shared__ int cursor[256];
    __shared__ int wsum[4];
    int t = threadIdx.x, cb = blockIdx.x;
    int lane = t & 63, wave = t >> 6;

    hist[t] = 0;
    __syncthreads();
    int c = ccount[cb];
    if (c > CAP) c = CAP;
    for (int i = t; i < c; i += 256) {
        u32 v = staged[cb * CAP + i];
        sdata[i] = v;
        atomicAdd(&hist[(v >> 16) & 255], 1);
    }
    __syncthreads();
    int d = hist[t];                 // true degree
    int pd = (d + 15) & ~15;         // padded length
    int s = pd;
#pragma unroll
    for (int off = 1; off < 64; off <<= 1) {
        int u = __shfl_up(s, off, 64);
        if (lane >= off) s += u;
    }
    if (lane == 63) wsum[wave] = s;
    __syncthreads();
    int wadd = 0;
#pragma unroll
    for (int w = 0; w < 4; w++) if (w < wave) wadd += wsum[w];
    int gb = cb * PCAP + (s - pd + wadd);   // padded base (bucket-local region)
    int node = cb * 256 + t;
    if (node < N_NODES) {
        info[node] = (u32)gb | ((u32)(pd >> 4) << 21);
        inv[node] = d > 0 ? 1.0f / (float)d : 0.0f;
    }
    cursor[t] = gb;
    __syncthreads();
    for (int i = t; i < c; i += 256) {
        u32 v = sdata[i];
        int pos = atomicAdd(&cursor[(v >> 16) & 255], 1);
        eidx[pos] = (u16)(v & 0xffffu);
    }
    // pad-fill with dummy src = N_NODES (zero row)
    for (int i = gb + d; i < gb + pd; i++) eidx[i] = (u16)N_NODES;
}

// Fused SAGE layer, 16-row tile. Phase 1 gathers from the fp8 shadow copy
// (half the bytes/line-requests of bf16; 6.4MB working set ~fits per-XCD L2),
// unpacks via v_cvt_pk_f32_fp8, accumulates f32. Phase 2: GEMM (bf16 A from
// global, mean from swizzled LDS).
template <int RELU, int OUTF32>
__global__ __launch_bounds__(256) void fused_layer(
    const u16* __restrict__ A, const u8* __restrict__ AF8,
    const u16* __restrict__ WpR, const u16* __restrict__ WpL,
    const float* __restrict__ bias, const float* __restrict__ inv,
    const u32* __restrict__ info, const u16* __restrict__ eidx,
    u16* __restrict__ outb, u8* __restrict__ outf8, float* __restrict__ outf) {
    __shared__ char mlds[16 * 256];   // 16 rows x 128 bf16, 16B-chunk XOR swizzle
    int wave = threadIdx.x >> 6, lane = threadIdx.x & 63;
    int rowbase = blockIdx.x * 16;
    int quad = lane >> 4, ql = lane & 15;

    int basek[4], rnds[4];
#pragma unroll
    for (int k = 0; k < 4; k++) {
        u32 ifo = info[rowbase + wave * 4 + k];
        basek[k] = (int)(ifo & 0x1FFFFFu);
        rnds[k]  = (int)(ifo >> 21);
    }
    int maxr = rnds[0];
#pragma unroll
    for (int k = 1; k < 4; k++) maxr = rnds[k] > maxr ? rnds[k] : maxr;

    float acc[4][8];
#pragma unroll
    for (int k = 0; k < 4; k++)
#pragma unroll
        for (int j = 0; j < 8; j++) acc[k][j] = 0.f;

#pragma unroll 1
    for (int r = 0; r < maxr; r++) {
        u32x2 g[4][4];
        // issue all loads first (16 eidx + 16 fp8-row gathers in flight)
#pragma unroll
        for (int k = 0; k < 4; k++) {
            if (r < rnds[k]) {                         // wave-uniform branch
                int i0 = basek[k] + r * 16 + quad;
                int s0 = eidx[i0], s1 = eidx[i0 + 4], s2 = eidx[i0 + 8], s3 = eidx[i0 + 12];
                g[k][0] = *(const u32x2*)(AF8 + (size_t)s0 * D + ql * 8);
                g[k][1] = *(const u32x2*)(AF8 + (size_t)s1 * D + ql * 8);
                g[k][2] = *(const u32x2*)(AF8 + (size_t)s2 * D + ql * 8);
                g[k][3] = *(const u32x2*)(AF8 + (size_t)s3 * D + ql * 8);
            }
        }
        // then unpack + accumulate
#pragma unroll
        for (int k = 0; k < 4; k++) {
            if (r < rnds[k]) {
#pragma unroll
                for (int j = 0; j < 4; j++) {
                    u32x2 v = g[k][j];
                    f32x2 f0 = __builtin_amdgcn_cvt_pk_f32_fp8((int)v.x, false);
                    f32x2 f1 = __builtin_amdgcn_cvt_pk_f32_fp8((int)v.x, true);
                    f32x2 f2 = __builtin_amdgcn_cvt_pk_f32_fp8((int)v.y, false);
                    f32x2 f3 = __builtin_amdgcn_cvt_pk_f32_fp8((int)v.y, true);
                    acc[k][0] += f0.x; acc[k][1] += f0.y;
                    acc[k][2] += f1.x; acc[k][3] += f1.y;
                    acc[k][4] += f2.x; acc[k][5] += f2.y;
                    acc[k][6] += f3.x; acc[k][7] += f3.y;
                }
            }
        }
    }

#pragma unroll
    for (int k = 0; k < 4; k++) {
#pragma unroll
        for (int j = 0; j < 8; j++) {
            acc[k][j] += __shfl_xor(acc[k][j], 16);
            acc[k][j] += __shfl_xor(acc[k][j], 32);
        }
        if (quad == 0) {
            int node = rowbase + wave * 4 + k;
            float iv = inv[node];
            u32x4 o;
            o.x = (u32)f32_to_bf16(acc[k][0] * iv) | ((u32)f32_to_bf16(acc[k][1] * iv) << 16);
            o.y = (u32)f32_to_bf16(acc[k][2] * iv) | ((u32)f32_to_bf16(acc[k][3] * iv) << 16);
            o.z = (u32)f32_to_bf16(acc[k][4] * iv) | ((u32)f32_to_bf16(acc[k][5] * iv) << 16);
            o.w = (u32)f32_to_bf16(acc[k][6] * iv) | ((u32)f32_to_bf16(acc[k][7] * iv) << 16);
            int lr = wave * 4 + k;
            *(u32x4*)(mlds + lr * 256 + ((ql ^ lr) & 15) * 16) = o;
        }
    }

    // B fragments loaded after the gather to keep gather-phase register pressure low.
    s16x8 bR[2][4], bL[2][4];
#pragma unroll
    for (int ct = 0; ct < 2; ct++) {
        int ctg = wave * 2 + ct;
#pragma unroll
        for (int ks = 0; ks < 4; ks++) {
            size_t off = (size_t)((ctg * 4 + ks) * 64 + lane) * 8;
            bR[ct][ks] = *(const s16x8*)(WpR + off);
            bL[ct][ks] = *(const s16x8*)(WpL + off);
        }
    }
    __syncthreads();

    // Phase 2: 16x128 GEMM; wave w owns cols [w*32, w*32+32).
    f32x4 acc2[2];
    acc2[0] = (f32x4){0.f, 0.f, 0.f, 0.f};
    acc2[1] = (f32x4){0.f, 0.f, 0.f, 0.f};
#pragma unroll
    for (int ks = 0; ks < 4; ks++) {
        s16x8 a1 = *(const s16x8*)(A + (size_t)(rowbase + ql) * D + ks * 32 + quad * 8);
        s16x8 a2 = *(const s16x8*)(mlds + ql * 256 + (((ks * 4 + quad) ^ ql) & 15) * 16);
#pragma unroll
        for (int ct = 0; ct < 2; ct++) {
            acc2[ct] = mfma16(a1, bR[ct][ks], acc2[ct]);
            acc2[ct] = mfma16(a2, bL[ct][ks], acc2[ct]);
        }
    }

    float bv[2];
#pragma unroll
    for (int ct = 0; ct < 2; ct++) bv[ct] = bias[wave * 32 + ct * 16 + ql];

#pragma unroll
    for (int i = 0; i < 4; i++) {
        int row = rowbase + quad * 4 + i;
        float mask = inv[row] > 0.f ? 1.f : 0.f;
#pragma unroll
        for (int ct = 0; ct < 2; ct++) {
            int col = wave * 32 + ct * 16 + ql;
            float v = acc2[ct][i] + mask * bv[ct];
            if (RELU) v = v > 0.f ? v : 0.f;
            if (OUTF32) {
                outf[(size_t)row * D + col] = v;
            } else {
                outb[(size_t)row * D + col] = f32_to_bf16(v);
                int pk = __builtin_amdgcn_cvt_pk_fp8_f32(v, v, 0, false);
                outf8[(size_t)row * D + col] = (u8)(pk & 0xff);
            }
        }
    }
}

extern "C" void kernel_launch(void* const* d_in, const int* in_sizes, int n_in,
                              void* d_out, int out_size, void* d_ws, size_t ws_size,
                              hipStream_t stream) {
    const float* x    = (const float*)d_in[0];
    const int*   edge = (const int*)d_in[1];
    const int*   src  = edge;
    const int*   dstn = edge + N_EDGES;
    const float* W0l  = (const float*)d_in[2];
    const float* b0l  = (const float*)d_in[3];
    const float* W0r  = (const float*)d_in[4];
    const float* W1l  = (const float*)d_in[5];
    const float* b1l  = (const float*)d_in[6];
    const float* W1r  = (const float*)d_in[7];
    float* out = (float*)d_out;

    char* p = (char*)d_ws;
    auto alloc = [&](size_t nb) { char* r = p; p += (nb + 255) & ~(size_t)255; return r; };
    int*   ccount = (int*)alloc((size_t)NBLK * 4);
    u32*   info   = (u32*)alloc((size_t)N_NODES * 4);
    float* inv    = (float*)alloc((size_t)N_NODES * 4);
    u32*   staged = (u32*)alloc((size_t)NBLK * CAP * 4);
    u16*   eidx   = (u16*)alloc((size_t)NBLK * PCAP * 2);
    u16*   xb     = (u16*)alloc((size_t)(N_NODES + 1) * D * 2);   // +1 zero row
    u16*   hb     = (u16*)alloc((size_t)(N_NODES + 1) * D * 2);   // +1 zero row
    u8*    xf8    = (u8*)alloc((size_t)(N_NODES + 1) * D);
    u8*    hf8    = (u8*)alloc((size_t)(N_NODES + 1) * D);
    u16*   Wp     = (u16*)alloc((size_t)4 * 16384 * 2);

    hipMemsetAsync(ccount, 0, (size_t)NBLK * 4, stream);

    prep_stage<<<CAST_BLOCKS + 33 + STAGE_BLOCKS, 256, 0, stream>>>(
        x, xb, hb, xf8, hf8, W0l, W0r, W1l, W1r, Wp, src, dstn, ccount, staged);
    fine_kernel<<<NBLK, 256, 0, stream>>>(ccount, staged, eidx, info, inv);

    int fblocks = N_NODES / 16;          // 3125 exactly
    const u16* WpL0 = Wp;                 // W0l
    const u16* WpR0 = Wp + 16384;         // W0r
    const u16* WpL1 = Wp + 2 * 16384;     // W1l
    const u16* WpR1 = Wp + 3 * 16384;     // W1r
    // Layer 0: h = relu( x@W0r + mean_x@W0l + mask*b0l ), h also stored fp8
    fused_layer<1, 0><<<fblocks, 256, 0, stream>>>(xb, xf8, WpR0, WpL0, b0l, inv, info, eidx, hb, hf8, nullptr);
    // Layer 1: out = h@W1r + mean_h@W1l + mask*b1l
    fused_layer<0, 1><<<fblocks, 256, 0, stream>>>(hb, hf8, WpR1, WpL1, b1l, inv, info, eidx, nullptr, nullptr, out);
}